// Round 1
// baseline (246.486 us; speedup 1.0000x reference)
//
#include <hip/hip_runtime.h>

#define CLS   19
#define NBINS 256
#define HWSZ  (512 * 512)      // 262144 = 2^18
#define NPIX  (8 * HWSZ)       // 2097152
#define HIST  (CLS * NBINS)    // 4864
#define NSUB  8

// ---------------------------------------------------------------------------
// Kernel 1: softmax + error binning into per-block packed histograms.
// Packed u32: low 16 bits = element count, high 16 bits = foreground count.
// Per-block pixel budget <= 32768 so neither field can overflow/carry.
// ---------------------------------------------------------------------------
__global__ __launch_bounds__(512)
void lovasz_hist(const float* __restrict__ logits, const int* __restrict__ labels,
                 unsigned* __restrict__ blk_hist, float* __restrict__ out,
                 int npix_per_blk) {
    __shared__ unsigned h[HIST];
    const int tid = threadIdx.x;
    for (int i = tid; i < HIST; i += 512) h[i] = 0u;
    if (blockIdx.x == 0 && tid == 0) out[0] = 0.f;   // d_out is poisoned each replay
    __syncthreads();

    const int base_p = blockIdx.x * npix_per_blk;
    for (int it = 0; it < npix_per_blk; it += 512) {
        const int p  = base_p + it + tid;            // grid exactly tiles NPIX
        const int n  = p >> 18;                      // HWSZ = 2^18
        const int hw = p & (HWSZ - 1);
        const float* bp = logits + (size_t)n * CLS * HWSZ + hw;

        float v[CLS];
        float m = -3.4e38f;
#pragma unroll
        for (int c = 0; c < CLS; ++c) {
            v[c] = bp[(size_t)c * HWSZ];             // coalesced per-class stream
            m = fmaxf(m, v[c]);
        }
        float s = 0.f;
#pragma unroll
        for (int c = 0; c < CLS; ++c) { v[c] = __expf(v[c] - m); s += v[c]; }
        const float inv = 1.f / s;
        const int lab = labels[p];
#pragma unroll
        for (int c = 0; c < CLS; ++c) {
            float e = v[c] * inv;                    // prob in [0,1]
            unsigned inc = 1u;
            if (c == lab) { e = 1.f - e; inc = 0x10001u; }   // |fg - p|, fg flagged
            int bin = (int)(e * (float)NBINS);       // tiny negatives trunc to 0
            bin = bin > (NBINS - 1) ? (NBINS - 1) : bin;
            atomicAdd(&h[c * NBINS + bin], inc);
        }
    }
    __syncthreads();
    unsigned* dst = blk_hist + (size_t)blockIdx.x * HIST;
    for (int i = tid; i < HIST; i += 512) dst[i] = h[i];     // plain store: no atomics,
                                                             // ws needs no pre-zero
}

// ---------------------------------------------------------------------------
// Kernel 2: unpack + partial-reduce block histograms over NSUB chunks.
// grid = (CLS, NSUB), block = NBINS threads (thread t == bin t).
// ---------------------------------------------------------------------------
__global__ __launch_bounds__(NBINS)
void lovasz_reduce(const unsigned* __restrict__ blk_hist,
                   unsigned* __restrict__ pc, unsigned* __restrict__ pf, int nblk) {
    const int c = blockIdx.x, sub = blockIdx.y, t = threadIdx.x;
    const int per = nblk / NSUB;
    unsigned cnt = 0, fg = 0;
    for (int b = sub * per; b < (sub + 1) * per; ++b) {
        const unsigned v = blk_hist[(size_t)b * HIST + c * NBINS + t];
        cnt += v & 0xFFFFu;                          // unpack BEFORE summing
        fg  += v >> 16;
    }
    pc[(sub * CLS + c) * NBINS + t] = cnt;
    pf[(sub * CLS + c) * NBINS + t] = fg;
}

// ---------------------------------------------------------------------------
// Kernel 3: per-class descending-bin scan -> Lovasz loss. grid = CLS blocks.
// Exact Jaccard at bin boundaries: J = 1 - (gts-f)/(gts+n-f), J(0,0) := 0.
// ---------------------------------------------------------------------------
__global__ __launch_bounds__(NBINS)
void lovasz_final(const unsigned* __restrict__ pc, const unsigned* __restrict__ pf,
                  float* __restrict__ out) {
    __shared__ unsigned scnt[NBINS], sfg[NBINS];
    __shared__ float part[NBINS / 64];
    const int c = blockIdx.x, t = threadIdx.x;

    unsigned cnt = 0, fg = 0;
    for (int s = 0; s < NSUB; ++s) {
        cnt += pc[(s * CLS + c) * NBINS + t];
        fg  += pf[(s * CLS + c) * NBINS + t];
    }
    scnt[t] = cnt; sfg[t] = fg;
    __syncthreads();

    unsigned nb = 0, fb = 0, g = 0;
    for (int b = t + 1; b < NBINS; ++b) { nb += scnt[b]; fb += sfg[b]; } // suffix (bins above = larger errors)
    for (int b = 0; b < NBINS; ++b) g += sfg[b];                          // gts

    const float gts = (float)g;
    const float nB = (float)nb,          fB = (float)fb;
    const float nA = nB + (float)cnt,    fA = fB + (float)fg;
    const float dB = gts + nB - fB;
    const float jB = dB > 0.f ? 1.f - (gts - fB) / dB : 0.f;   // J(0,0)=0 when gts=0
    const float dA = gts + nA - fA;
    const float jA = dA > 0.f ? 1.f - (gts - fA) / dA : 0.f;
    float contrib = (((float)t + 0.5f) * (1.f / NBINS)) * (jA - jB);

    // wave64 reduce, then cross-wave via LDS
    for (int off = 32; off > 0; off >>= 1) contrib += __shfl_down(contrib, off);
    if ((t & 63) == 0) part[t >> 6] = contrib;
    __syncthreads();
    if (t == 0) {
        float loss_c = 0.f;
        for (int w = 0; w < NBINS / 64; ++w) loss_c += part[w];
        atomicAdd(out, loss_c * (1.f / (float)CLS));
    }
}

extern "C" void kernel_launch(void* const* d_in, const int* in_sizes, int n_in,
                              void* d_out, int out_size, void* d_ws, size_t ws_size,
                              hipStream_t stream) {
    const float* logits = (const float*)d_in[0];
    const int*   labels = (const int*)d_in[1];
    float*       out    = (float*)d_out;

    int nblk = 512;                                   // 4096 px/block
    size_t need = (size_t)nblk * HIST * 4 + 2 * (size_t)NSUB * HIST * 4;
    if (ws_size < need) nblk = 64;                    // fallback: 32768 px/block (u16-safe)

    unsigned* blk_hist = (unsigned*)d_ws;
    unsigned* pc = blk_hist + (size_t)nblk * HIST;
    unsigned* pf = pc + (size_t)NSUB * HIST;

    lovasz_hist<<<nblk, 512, 0, stream>>>(logits, labels, blk_hist, out, NPIX / nblk);
    lovasz_reduce<<<dim3(CLS, NSUB), NBINS, 0, stream>>>(blk_hist, pc, pf, nblk);
    lovasz_final<<<CLS, NBINS, 0, stream>>>(pc, pf, out);
}